// Round 5
// baseline (824.040 us; speedup 1.0000x reference)
//
#include <hip/hip_runtime.h>
#include <hip/hip_bf16.h>
#include <math.h>

// GLA cross-attention — round 12:
//  r11 post-mortem: WRITE_SIZE 859MB, VGPR_Count=104 — with plain
//  __launch_bounds__(256) the allocator's occupancy heuristic capped regs at
//  ~104 and spilled the 32 prefetch VGPRs in-loop (structure needs ~140).
//  r8 failed from a forced cap (256,4); r11 from the default heuristic cap.
//  r12:
//   (a) attn: __launch_bounds__(256, 2) -> VGPR ceiling 256 >> ~140 needed;
//       no spill mode below 256. ~3 waves/SIMD, 3 blocks/CU (= r7 occupancy)
//       with the T14 reg-prefetch actually functional.
//   (b) fuse the 4 up-projection GEMMs into ONE launch (gridDim.z=4) via
//       z-stride params on gemm_mfma (other call sites pass 0) — removes 3
//       serialized 512-block launch tails.
//  Everything else byte-identical to r11 (whose math PASSED; only perf wrong).
//
// ws float-offset map (alias notes; top = 49,807,360 f = 199.2 MB):
//   attn_out_b u16 @ 0 | ml f32 @ 2,097,152 | Wot u16 @ f4,194,304
//   xkvb u16 @ 0 (dead after stage 9) | ckv f32 @ 8,388,608 (dead after 10)
//   Opart f32 @ 8,388,608 (aliases dead ckv)
//   xqb/WdQt/q_lat/q_lat_b/WuQt in 8,388,608..13,631,488 (dead pre-stage-9)
//   ckv_b u16 @ 16,777,216 | kvgb u16 @ 20,971,520 | vt u16 @ 37,748,736
//   qb u16 @ 46,137,344 | WdKVt u16 @ 48,234,496 | Wukvt u16 @ 49,283,072

typedef __attribute__((ext_vector_type(8))) short short8;
typedef __attribute__((ext_vector_type(4))) float f32x4;

__device__ __forceinline__ ushort f2bf(float x) {
    __hip_bfloat16 h = __float2bfloat16(x);
    return *reinterpret_cast<ushort*>(&h);
}

// XOR swizzle in units of shorts: permutes 8-short (16B) blocks within each
// 64/128-short row by the low 3 row bits. Bijective; keeps 16B alignment.
#define SWZ(row, col) ((col) ^ (((row) & 7) << 3))

// async global->LDS, 16B per lane (gemm_mfma staging).
__device__ __forceinline__ void gload16(const ushort* g, ushort* l)
{
    __builtin_amdgcn_global_load_lds(
        (const __attribute__((address_space(1))) void*)g,
        (__attribute__((address_space(3))) void*)l, 16, 0, 0);
}

// ---------- elementwise fp32 -> bf16 cast, 8 elems/thread (VERIFIED r6)
__global__ __launch_bounds__(256) void cast_bf16(const float* __restrict__ src,
        ushort* __restrict__ dst)
{
    size_t i = ((size_t)blockIdx.x * 256 + threadIdx.x) * 8;
    float4 a = *(const float4*)(src + i);
    float4 b = *(const float4*)(src + i + 4);
    ushort u[8] = {f2bf(a.x), f2bf(a.y), f2bf(a.z), f2bf(a.w),
                   f2bf(b.x), f2bf(b.y), f2bf(b.z), f2bf(b.w)};
    *(uint4*)(dst + i) = *(uint4*)u;
}

// ---------- transpose + cast (VERIFIED r6)
__global__ __launch_bounds__(256) void transpose_cast(const float* __restrict__ src,
        ushort* __restrict__ dst, int srl, int dstld, int remap,
        long src_z, long dst_z)
{
    __shared__ ushort tile[64][68];
    const int k0 = blockIdx.x * 64;
    const int n0 = blockIdx.y * 64;
    src += (size_t)blockIdx.z * src_z;
    dst += (size_t)blockIdx.z * dst_z;
    const int cb = n0 + (remap ? (n0 >> 7) * 64 : 0);
    const int t = threadIdx.x;
    {
        int r = t >> 4, c4 = t & 15;
        #pragma unroll
        for (int i = 0; i < 4; ++i) {
            float4 v = *(const float4*)(src + (size_t)(k0 + r + 16 * i) * srl + cb + c4 * 4);
            tile[r + 16 * i][c4 * 4 + 0] = f2bf(v.x);
            tile[r + 16 * i][c4 * 4 + 1] = f2bf(v.y);
            tile[r + 16 * i][c4 * 4 + 2] = f2bf(v.z);
            tile[r + 16 * i][c4 * 4 + 3] = f2bf(v.w);
        }
    }
    __syncthreads();
    {
        int n = t >> 4, k4 = t & 15;
        #pragma unroll
        for (int i = 0; i < 4; ++i) {
            ushort4 v;
            v.x = tile[k4 * 4 + 0][n + 16 * i];
            v.y = tile[k4 * 4 + 1][n + 16 * i];
            v.z = tile[k4 * 4 + 2][n + 16 * i];
            v.w = tile[k4 * 4 + 3][n + 16 * i];
            *(ushort4*)(dst + (size_t)(n0 + n + 16 * i) * dstld + k0 + k4 * 4) = v;
        }
    }
}

// ---------- MFMA bf16 GEMM (VERIFIED r9 staging; r12 adds z-strides for
// fused batched launches — a_z/b_z in ushort elems, c_z in BYTES; pass 0 for 2D)
__global__ __launch_bounds__(256) void gemm_mfma(const ushort* __restrict__ A,
        const ushort* __restrict__ Bt, void* __restrict__ Cv,
        int M, int N, int K, int lda, int ldb, int ldc, int obf16, float scale,
        long a_z, long b_z, long c_z)
{
    __shared__ ushort As[128 * 64];
    __shared__ ushort Bs[128 * 64];
    A  += (size_t)blockIdx.z * a_z;
    Bt += (size_t)blockIdx.z * b_z;
    Cv  = (void*)((char*)Cv + (size_t)blockIdx.z * c_z);
    const int tid = threadIdx.x;
    const int w = tid >> 6, lane = tid & 63;
    const int quad = lane >> 4, l16 = lane & 15;
    const int wm = (w >> 1) * 64, wn = (w & 1) * 64;
    const int m0 = blockIdx.y * 128, n0 = blockIdx.x * 128;

    f32x4 acc[4][4];
    #pragma unroll
    for (int i = 0; i < 4; ++i)
        #pragma unroll
        for (int j = 0; j < 4; ++j) acc[i][j] = (f32x4){0.f, 0.f, 0.f, 0.f};

    const int srow = lane >> 3;
    const int scol = ((lane & 7) * 8) ^ ((srow & 7) << 3);   // (row&7)==srow&7

    for (int k0 = 0; k0 < K; k0 += 64) {
        __syncthreads();
        #pragma unroll
        for (int i = 0; i < 4; ++i) {
            int r = w * 32 + i * 8 + srow;
            gload16(A + (size_t)(m0 + r) * lda + k0 + scol, &As[w * 2048 + i * 512]);
            gload16(Bt + (size_t)(n0 + r) * ldb + k0 + scol, &Bs[w * 2048 + i * 512]);
        }
        __syncthreads();
        #pragma unroll
        for (int kc = 0; kc < 2; ++kc) {
            short8 af[4], bf[4];
            #pragma unroll
            for (int i = 0; i < 4; ++i) {
                int ra = wm + i * 16 + l16;
                int rb = wn + i * 16 + l16;
                af[i] = *(const short8*)&As[ra * 64 + SWZ(ra, kc * 32 + quad * 8)];
                bf[i] = *(const short8*)&Bs[rb * 64 + SWZ(rb, kc * 32 + quad * 8)];
            }
            #pragma unroll
            for (int i = 0; i < 4; ++i)
                #pragma unroll
                for (int j = 0; j < 4; ++j)
                    acc[i][j] = __builtin_amdgcn_mfma_f32_16x16x32_bf16(af[i], bf[j], acc[i][j], 0, 0, 0);
        }
    }
    if (!obf16) {
        float* C = (float*)Cv;
        #pragma unroll
        for (int i = 0; i < 4; ++i)
            #pragma unroll
            for (int r = 0; r < 4; ++r) {
                float* cp = C + (size_t)(m0 + wm + i * 16 + quad * 4 + r) * ldc + n0 + wn + l16;
                #pragma unroll
                for (int j = 0; j < 4; ++j) cp[j * 16] = acc[i][j][r] * scale;
            }
    } else {
        ushort* C = (ushort*)Cv;
        #pragma unroll
        for (int i = 0; i < 4; ++i)
            #pragma unroll
            for (int r = 0; r < 4; ++r) {
                ushort* cp = C + (size_t)(m0 + wm + i * 16 + quad * 4 + r) * ldc + n0 + wn + l16;
                #pragma unroll
                for (int j = 0; j < 4; ++j) cp[j * 16] = f2bf(acc[i][j][r] * scale);
            }
    }
}

// ---------- coalesced rmsnorm, 512 cols, wave per row, bf16 out (VERIFIED r7)
__global__ __launch_bounds__(256) void rms_q_wave(const float* __restrict__ x,
        const float* __restrict__ w, ushort* __restrict__ dst)
{
    const int row = blockIdx.x * 4 + (threadIdx.x >> 6);
    const int lane = threadIdx.x & 63;
    const float* p = x + (size_t)row * 512;
    float4 v0 = *(const float4*)(p + lane * 4);
    float4 v1 = *(const float4*)(p + 256 + lane * 4);
    float ss = v0.x*v0.x + v0.y*v0.y + v0.z*v0.z + v0.w*v0.w
             + v1.x*v1.x + v1.y*v1.y + v1.z*v1.z + v1.w*v1.w;
    #pragma unroll
    for (int m = 1; m < 64; m <<= 1) ss += __shfl_xor(ss, m);
    float inv = rsqrtf(ss * (1.f / 512.f) + 1e-6f);
    float4 w0 = *(const float4*)(w + lane * 4);
    float4 w1 = *(const float4*)(w + 256 + lane * 4);
    ushort* dp = dst + (size_t)row * 512;
    ushort4 o0, o1;
    o0.x = f2bf(v0.x * inv * w0.x); o0.y = f2bf(v0.y * inv * w0.y);
    o0.z = f2bf(v0.z * inv * w0.z); o0.w = f2bf(v0.w * inv * w0.w);
    o1.x = f2bf(v1.x * inv * w1.x); o1.y = f2bf(v1.y * inv * w1.y);
    o1.z = f2bf(v1.z * inv * w1.z); o1.w = f2bf(v1.w * inv * w1.w);
    *(ushort4*)(dp + lane * 4)       = o0;
    *(ushort4*)(dp + 256 + lane * 4) = o1;
}

// ---------- coalesced grouped rmsnorm, 256 cols/group, wave per (row,g) (VERIFIED r7)
__global__ __launch_bounds__(256) void rms_kv_wave(const float* __restrict__ x,
        const float* __restrict__ w, ushort* __restrict__ dst)
{
    const int idx = blockIdx.x * 4 + (threadIdx.x >> 6);   // 0..32767
    const int lane = threadIdx.x & 63;
    const int r = idx >> 2, g = idx & 3;
    const float* p = x + (size_t)r * 1024 + g * 256;
    float4 v = *(const float4*)(p + lane * 4);
    float ss = v.x*v.x + v.y*v.y + v.z*v.z + v.w*v.w;
    #pragma unroll
    for (int m = 1; m < 64; m <<= 1) ss += __shfl_xor(ss, m);
    float inv = rsqrtf(ss * (1.f / 256.f) + 1e-6f);
    float4 wv = *(const float4*)(w + g * 256 + lane * 4);
    ushort4 o;
    o.x = f2bf(v.x * inv * wv.x); o.y = f2bf(v.y * inv * wv.y);
    o.z = f2bf(v.z * inv * wv.z); o.w = f2bf(v.w * inv * wv.w);
    *(ushort4*)(dst + (size_t)r * 1024 + g * 256 + lane * 4) = o;
}

// ---------- V transpose (VERIFIED r5/r6)
__global__ __launch_bounds__(256) void transpose_v(const ushort* __restrict__ KVb,
                                                   ushort* __restrict__ Vt)
{
    __shared__ ushort tile[64][66];
    const int s0 = blockIdx.x * 64;
    const int d0 = blockIdx.y * 64;
    const int bh = blockIdx.z;
    const int b = bh >> 4, h = bh & 15, g = h >> 2, p = h & 3;
    const int t = threadIdx.x;
    const ushort* src = KVb + (size_t)g * 8388608ull + (size_t)(b * 4096) * 1024 + p * 256 + 128;
    {
        int sl = t >> 4, c4 = t & 15;
        #pragma unroll
        for (int i = 0; i < 4; ++i) {
            int s = sl + 16 * i;
            ushort4 v = *(const ushort4*)(src + (size_t)(s0 + s) * 1024 + d0 + c4 * 4);
            tile[s][c4 * 4 + 0] = v.x; tile[s][c4 * 4 + 1] = v.y;
            tile[s][c4 * 4 + 2] = v.z; tile[s][c4 * 4 + 3] = v.w;
        }
    }
    __syncthreads();
    {
        int dl = t >> 4, s4 = t & 15;
        ushort* dst = Vt + (size_t)(b * 16 + h) * 128 * 4096;
        #pragma unroll
        for (int i = 0; i < 4; ++i) {
            int d = dl + 16 * i;
            ushort4 v;
            v.x = tile[s4 * 4 + 0][d]; v.y = tile[s4 * 4 + 1][d];
            v.z = tile[s4 * 4 + 2][d]; v.w = tile[s4 * 4 + 3][d];
            *(ushort4*)(dst + (size_t)(d0 + d) * 4096 + s0 + s4 * 4) = v;
        }
    }
}

// full QK^T -> online softmax (defer-max THR=8) -> PV for the tile in Ks/VsT
#define ATTN_COMPUTE() do {                                                    \
    f32x4 accS[4];                                                             \
    _Pragma("unroll")                                                          \
    for (int st = 0; st < 4; ++st) accS[st] = (f32x4){0.f, 0.f, 0.f, 0.f};     \
    __builtin_amdgcn_s_setprio(1);                                             \
    _Pragma("unroll")                                                          \
    for (int kc = 0; kc < 4; ++kc) {                                           \
        _Pragma("unroll")                                                      \
        for (int st = 0; st < 4; ++st) {                                       \
            int krow = st * 16 + l16;                                          \
            short8 kf = *(const short8*)&Ks[krow * 128 + SWZ(krow, kc * 32 + quad * 8)]; \
            accS[st] = __builtin_amdgcn_mfma_f32_16x16x32_bf16(qf[kc], kf, accS[st], 0, 0, 0); \
        }                                                                      \
    }                                                                          \
    __builtin_amdgcn_s_setprio(0);                                             \
    _Pragma("unroll")                                                          \
    for (int r = 0; r < 4; ++r) {                                              \
        float tm = fmaxf(fmaxf(accS[0][r], accS[1][r]), fmaxf(accS[2][r], accS[3][r])); \
        _Pragma("unroll")                                                      \
        for (int msk = 1; msk < 16; msk <<= 1) tm = fmaxf(tm, __shfl_xor(tm, msk)); \
        if (tm > m_i[r] + 8.f) {                                               \
            float alpha = __expf(m_i[r] - tm);                                 \
            l_i[r] *= alpha;                                                   \
            _Pragma("unroll")                                                  \
            for (int dt = 0; dt < 8; ++dt) accO[dt][r] *= alpha;               \
            m_i[r] = tm;                                                       \
        }                                                                      \
        const float mn = m_i[r];                                               \
        float rs = 0.f;                                                        \
        const int prow = quad * 4 + r;                                         \
        _Pragma("unroll")                                                      \
        for (int st = 0; st < 4; ++st) {                                       \
            float e = __expf(accS[st][r] - mn);                                \
            rs += e;                                                           \
            Ps[(w * 16 + prow) * 64 + SWZ(prow, st * 16 + l16)] = f2bf(e);     \
        }                                                                      \
        _Pragma("unroll")                                                      \
        for (int msk = 1; msk < 16; msk <<= 1) rs += __shfl_xor(rs, msk);      \
        l_i[r] += rs;                                                          \
    }                                                                          \
    short8 pf[2];                                                              \
    _Pragma("unroll")                                                          \
    for (int sc = 0; sc < 2; ++sc)                                             \
        pf[sc] = *(const short8*)&Ps[(w * 16 + l16) * 64 + SWZ(l16, sc * 32 + quad * 8)]; \
    __builtin_amdgcn_s_setprio(1);                                             \
    _Pragma("unroll")                                                          \
    for (int sc = 0; sc < 2; ++sc) {                                           \
        _Pragma("unroll")                                                      \
        for (int dt = 0; dt < 8; ++dt) {                                       \
            int vrow = dt * 16 + l16;                                          \
            short8 vf = *(const short8*)&VsT[vrow * 64 + SWZ(vrow, sc * 32 + quad * 8)]; \
            accO[dt] = __builtin_amdgcn_mfma_f32_16x16x32_bf16(pf[sc], vf, accO[dt], 0, 0, 0); \
        }                                                                      \
    }                                                                          \
    __builtin_amdgcn_s_setprio(0);                                             \
} while (0)

// ---------- MFMA flash attention, SPLIT-s=2, round-12: T14 reg-prefetch with
// a VGPR budget the structure can live in: __launch_bounds__(256, 2) caps at
// 256 regs (needs ~140) — no spill mode, ~3 waves/SIMD, 3 blocks/CU.
// Loop: barrier(A) [prefetch landed during prior compute] -> ds_write -> 
// barrier(B) -> issue prefetch i+1 -> compute tile i.
__global__ __launch_bounds__(256, 2) void attn_mfma_split(const ushort* __restrict__ Qb,
        const ushort* __restrict__ KVb, const ushort* __restrict__ Vt,
        float* __restrict__ Opart, float* __restrict__ ml)
{
    __shared__ ushort Ks[64 * 128];      // 16384 B, swizzled rows of 128 shorts
    __shared__ ushort VsT[128 * 64];     // 16384 B, swizzled rows of 64 shorts
    __shared__ ushort Ps[4 * 16 * 64];   //  8192 B, per-wave 16x64, swizzled

    const int q0 = blockIdx.x * 64;
    const int h = blockIdx.y;
    const int b = blockIdx.z >> 1, chunk = blockIdx.z & 1;
    const int g = h >> 2, p = h & 3;
    const int tid = threadIdx.x;
    const int w = tid >> 6, lane = tid & 63;
    const int quad = lane >> 4, l16 = lane & 15;
    const int sbase = chunk * 2048;

    const ushort* qg = Qb + (size_t)(b * 1024 + q0) * 2048 + h * 128;
    const ushort* kg = KVb + (size_t)g * 8388608ull + (size_t)(b * 4096 + sbase) * 1024 + p * 256;
    const ushort* vg = Vt + (size_t)(b * 16 + h) * 128 * 4096 + sbase;

    // staging geometry (256 threads cover each 64x128 / 128x64 tile):
    const int kr  = tid >> 4;            // K rows kr+16i, col kc8 (shorts)
    const int kc8 = (tid & 15) * 8;
    const int vd  = tid >> 3;            // V rows vd+32i, col vs8 (shorts)
    const int vs8 = (tid & 7) * 8;

    // issue tile-0 K/V loads early; they drain while Q is staged/read
    uint4 krg[4], vrg[4];
    #pragma unroll
    for (int i = 0; i < 4; ++i)
        krg[i] = *(const uint4*)(kg + (size_t)(kr + 16 * i) * 1024 + kc8);
    #pragma unroll
    for (int i = 0; i < 4; ++i)
        vrg[i] = *(const uint4*)(vg + (size_t)(vd + 32 * i) * 4096 + vs8);

    // stage Q through Ks (swizzled), pull per-lane fragments
    #pragma unroll
    for (int i = 0; i < 4; ++i) {
        int r = kr + 16 * i;
        *(uint4*)&Ks[r * 128 + SWZ(r, kc8)] = *(const uint4*)(qg + (size_t)r * 2048 + kc8);
    }
    __syncthreads();
    short8 qf[4];
    {
        int qr = w * 16 + l16;
        #pragma unroll
        for (int kc = 0; kc < 4; ++kc)
            qf[kc] = *(const short8*)&Ks[qr * 128 + SWZ(qr, kc * 32 + quad * 8)];
    }

    f32x4 accO[8];
    float m_i[4], l_i[4];
    #pragma unroll
    for (int dt = 0; dt < 8; ++dt) accO[dt] = (f32x4){0.f, 0.f, 0.f, 0.f};
    #pragma unroll
    for (int r = 0; r < 4; ++r) { m_i[r] = -INFINITY; l_i[r] = 0.f; }

    for (int s0 = 0; s0 < 2048; s0 += 64) {
        __syncthreads();                  // (A) all waves done reading tiles
                                          //     (incl. qf reads at s0=0);
                                          //     prefetch landed during compute
        #pragma unroll
        for (int i = 0; i < 4; ++i) {
            int r = kr + 16 * i;
            *(uint4*)&Ks[r * 128 + SWZ(r, kc8)] = krg[i];
        }
        #pragma unroll
        for (int i = 0; i < 4; ++i) {
            int d = vd + 32 * i;
            *(uint4*)&VsT[d * 64 + SWZ(d, vs8)] = vrg[i];
        }
        __syncthreads();                  // (B) writes visible to all waves
        if (s0 + 64 < 2048) {             // prefetch next tile into regs;
            #pragma unroll                // HBM latency hides under compute
            for (int i = 0; i < 4; ++i)
                krg[i] = *(const uint4*)(kg + (size_t)(s0 + 64 + kr + 16 * i) * 1024 + kc8);
            #pragma unroll
            for (int i = 0; i < 4; ++i)
                vrg[i] = *(const uint4*)(vg + (size_t)(vd + 32 * i) * 4096 + s0 + 64 + vs8);
        }
        ATTN_COMPUTE();
    }

    // epilogue: unnormalized fp32 partials + (m,l)
    const int qrow = q0 + w * 16 + quad * 4;
    float* ob = Opart + (size_t)((chunk * 2 + b) * 1024 + qrow) * 2048 + h * 128 + l16;
    #pragma unroll
    for (int r = 0; r < 4; ++r)
        #pragma unroll
        for (int dt = 0; dt < 8; ++dt)
            ob[(size_t)r * 2048 + dt * 16] = accO[dt][r];
    if (l16 == 0) {
        #pragma unroll
        for (int r = 0; r < 4; ++r) {
            size_t mi = ((size_t)((chunk * 2 + b) * 1024 + qrow + r) * 16 + h) * 2;
            ml[mi] = m_i[r];
            ml[mi + 1] = l_i[r];
        }
    }
}

// ---------- merge the 2 s-chunks: one wave per (b,q,h); lane owns d=lane, lane+64
__global__ __launch_bounds__(256) void attn_merge(const float* __restrict__ Opart,
        const float* __restrict__ ml, ushort* __restrict__ Om)
{
    const int idx = blockIdx.x * 4 + (threadIdx.x >> 6);  // 0..32767
    const int lane = threadIdx.x & 63;
    const int h = idx & 15;
    const int q = (idx >> 4) & 1023;
    const int b = idx >> 14;

    size_t m1i = ((size_t)((0 * 2 + b) * 1024 + q) * 16 + h) * 2;
    size_t m2i = ((size_t)((1 * 2 + b) * 1024 + q) * 16 + h) * 2;
    float m1 = ml[m1i], l1 = ml[m1i + 1];
    float m2 = ml[m2i], l2 = ml[m2i + 1];
    float M = fmaxf(m1, m2);
    float w1 = __expf(m1 - M), w2 = __expf(m2 - M);
    float invL = 1.f / (l1 * w1 + l2 * w2);

    const float* o1 = Opart + (size_t)((0 * 2 + b) * 1024 + q) * 2048 + h * 128;
    const float* o2 = Opart + (size_t)((1 * 2 + b) * 1024 + q) * 2048 + h * 128;
    ushort* ob = Om + (size_t)(b * 1024 + q) * 2048 + h * 128;
    ob[lane]      = f2bf((o1[lane]      * w1 + o2[lane]      * w2) * invL);
    ob[lane + 64] = f2bf((o1[lane + 64] * w1 + o2[lane + 64] * w2) * invL);
}

extern "C" void kernel_launch(void* const* d_in, const int* in_sizes, int n_in,
                              void* d_out, int out_size, void* d_ws, size_t ws_size,
                              hipStream_t stream)
{
    (void)in_sizes; (void)n_in; (void)out_size; (void)ws_size;
    const float* x_q       = (const float*)d_in[0];
    const float* x_kv      = (const float*)d_in[1];
    const float* W_dQ      = (const float*)d_in[2];
    const float* q_norm_w  = (const float*)d_in[3];
    const float* W_uQ      = (const float*)d_in[4];
    const float* W_dKV     = (const float*)d_in[5];
    const float* kv_norm_w = (const float*)d_in[6];
    const float* W_ukv     = (const float*)d_in[7];
    const float* W_o       = (const float*)d_in[8];
    float* out = (float*)d_out;

    float* ws = (float*)d_ws;
    ushort* xkvb       = (ushort*)ws;
    ushort* attn_out_b = (ushort*)ws;
    float*  mlbuf      = ws + 2097152ull;
    ushort* Wot        = (ushort*)(ws + 4194304ull);
    float*  ckv        = ws + 8388608ull;
    float*  Opart      = ws + 8388608ull;                 // aliases dead ckv
    ushort* xqb        = (ushort*)(ws + 8388608ull);      // pre-stage-9 only
    ushort* WdQt       = (ushort*)(ws + 10485760ull);
    float*  q_lat      = ws + 11010048ull;
    ushort* q_lat_b    = (ushort*)(ws + 12058624ull);
    ushort* WuQt       = (ushort*)(ws + 12582912ull);
    ushort* ckv_b      = (ushort*)(ws + 16777216ull);
    ushort* kvgb       = (ushort*)(ws + 20971520ull);
    ushort* vt         = (ushort*)(ws + 37748736ull);
    ushort* qb         = (ushort*)(ws + 46137344ull);
    ushort* WdKVt      = (ushort*)(ws + 48234496ull);
    ushort* Wukvt      = (ushort*)(ws + 49283072ull);

    const float qscale = 0.08838834764831845f;            // 1/sqrt(128)

    // 1-3) q_lat = bf16(x_q) @ bf16(W_dQ)
    cast_bf16<<<2048, 256, 0, stream>>>(x_q, xqb);
    transpose_cast<<<dim3(32, 8, 1), 256, 0, stream>>>(W_dQ, WdQt, 512, 2048, 0, 0, 0);
    gemm_mfma<<<dim3(4, 16), 256, 0, stream>>>(xqb, WdQt, q_lat, 2048, 512, 2048, 2048, 2048, 512, 0, 1.f, 0, 0, 0);
    // 4) rmsnorm -> bf16 (coalesced)
    rms_q_wave<<<512, 256, 0, stream>>>(q_lat, q_norm_w, q_lat_b);
    // 5-6) qb = (q_lat_b @ W_uQ[:, head :128]) * qscale
    transpose_cast<<<dim3(8, 32, 1), 256, 0, stream>>>(W_uQ, WuQt, 3072, 512, 1, 0, 0);
    gemm_mfma<<<dim3(16, 16), 256, 0, stream>>>(q_lat_b, WuQt, qb, 2048, 2048, 512, 512, 512, 2048, 1, qscale, 0, 0, 0);
    // 7-9) ckv = bf16(x_kv) @ bf16(W_dKV[:, :1024])
    cast_bf16<<<8192, 256, 0, stream>>>(x_kv, xkvb);
    transpose_cast<<<dim3(32, 16, 1), 256, 0, stream>>>(W_dKV, WdKVt, 1088, 2048, 0, 0, 0);
    gemm_mfma<<<dim3(8, 64), 256, 0, stream>>>(xkvb, WdKVt, ckv, 8192, 1024, 2048, 2048, 2048, 1024, 0, 1.f, 0, 0, 0);
    // 10) grouped rmsnorm -> bf16 (coalesced)
    rms_kv_wave<<<8192, 256, 0, stream>>>(ckv, kv_norm_w, ckv_b);
    // 11-12) kv up-projection, all 4 groups in ONE launch (z = group)
    transpose_cast<<<dim3(4, 16, 4), 256, 0, stream>>>(W_ukv, Wukvt, 1024, 256, 0, 262144, 262144);
    gemm_mfma<<<dim3(8, 64, 4), 256, 0, stream>>>(ckv_b, Wukvt, kvgb,
                                                  8192, 1024, 256, 1024, 256, 1024, 1, 1.f,
                                                  256, 262144, 16777216);
    // 13) V transpose
    transpose_v<<<dim3(64, 2, 32), 256, 0, stream>>>(kvgb, vt);
    // 14) split-s MFMA flash attention + merge
    attn_mfma_split<<<dim3(16, 16, 4), 256, 0, stream>>>(qb, kvgb, vt, Opart, mlbuf);
    attn_merge<<<8192, 256, 0, stream>>>(Opart, mlbuf, attn_out_b);
    // 15-16) out = attn_out_b @ bf16(W_o)
    transpose_cast<<<dim3(32, 32, 1), 256, 0, stream>>>(W_o, Wot, 2048, 2048, 0, 0, 0);
    gemm_mfma<<<dim3(16, 16), 256, 0, stream>>>(attn_out_b, Wot, out, 2048, 2048, 2048, 2048, 2048, 2048, 0, 1.f, 0, 0, 0);
}

// Round 6
// 556.875 us; speedup vs baseline: 1.4798x; 1.4798x over previous
//
#include <hip/hip_runtime.h>
#include <hip/hip_bf16.h>
#include <math.h>

// GLA cross-attention — round 13:
//  r12 post-mortem: allocator spilled prefetch regs at EVERY budget hint
//  (r8 cap, r11 default, r12 min-waves): VGPR reg-prefetch is dead.
//  r13: T4 counted-vmcnt pipeline with RAW s_barrier (m218 mechanism):
//   - double-buffered Ks0/Vs0 / Ks1/Vs1 (72KB LDS, 2 blocks/CU);
//   - per tile: compute(cur) -> s_barrier -> STAGE(cur, tile+2) ->
//     s_waitcnt vmcnt(8) [only tile+1's loads; tile+2's 8 stay in flight
//     through both barriers and the whole next compute] -> s_barrier;
//   - NO __syncthreads in the loop (its mandatory vmcnt(0) drain was the
//     serialization in r7/r9/r10);
//   - compute body byte-identical to r9 (clean 108-VGPR, no spill mode).
//  Everything else identical to r12 (passed): batched up-proj GEMM, r9 GEMM
//  staging, r7 rms/transpose kernels.
//
// ws float-offset map (alias notes; top = 49,807,360 f = 199.2 MB):
//   attn_out_b u16 @ 0 | ml f32 @ 2,097,152 | Wot u16 @ f4,194,304
//   xkvb u16 @ 0 (dead after stage 9) | ckv f32 @ 8,388,608 (dead after 10)
//   Opart f32 @ 8,388,608 (aliases dead ckv)
//   xqb/WdQt/q_lat/q_lat_b/WuQt in 8,388,608..13,631,488 (dead pre-stage-9)
//   ckv_b u16 @ 16,777,216 | kvgb u16 @ 20,971,520 | vt u16 @ 37,748,736
//   qb u16 @ 46,137,344 | WdKVt u16 @ 48,234,496 | Wukvt u16 @ 49,283,072

typedef __attribute__((ext_vector_type(8))) short short8;
typedef __attribute__((ext_vector_type(4))) float f32x4;

__device__ __forceinline__ ushort f2bf(float x) {
    __hip_bfloat16 h = __float2bfloat16(x);
    return *reinterpret_cast<ushort*>(&h);
}

// XOR swizzle in units of shorts: permutes 8-short (16B) blocks within each
// 64/128-short row by the low 3 row bits. Bijective; keeps 16B alignment.
#define SWZ(row, col) ((col) ^ (((row) & 7) << 3))

// async global->LDS, 16B per lane. LDS dest wave-uniform; global src per-lane.
__device__ __forceinline__ void gload16(const ushort* g, ushort* l)
{
    __builtin_amdgcn_global_load_lds(
        (const __attribute__((address_space(1))) void*)g,
        (__attribute__((address_space(3))) void*)l, 16, 0, 0);
}

// ---------- elementwise fp32 -> bf16 cast, 8 elems/thread (VERIFIED r6)
__global__ __launch_bounds__(256) void cast_bf16(const float* __restrict__ src,
        ushort* __restrict__ dst)
{
    size_t i = ((size_t)blockIdx.x * 256 + threadIdx.x) * 8;
    float4 a = *(const float4*)(src + i);
    float4 b = *(const float4*)(src + i + 4);
    ushort u[8] = {f2bf(a.x), f2bf(a.y), f2bf(a.z), f2bf(a.w),
                   f2bf(b.x), f2bf(b.y), f2bf(b.z), f2bf(b.w)};
    *(uint4*)(dst + i) = *(uint4*)u;
}

// ---------- transpose + cast (VERIFIED r6)
__global__ __launch_bounds__(256) void transpose_cast(const float* __restrict__ src,
        ushort* __restrict__ dst, int srl, int dstld, int remap,
        long src_z, long dst_z)
{
    __shared__ ushort tile[64][68];
    const int k0 = blockIdx.x * 64;
    const int n0 = blockIdx.y * 64;
    src += (size_t)blockIdx.z * src_z;
    dst += (size_t)blockIdx.z * dst_z;
    const int cb = n0 + (remap ? (n0 >> 7) * 64 : 0);
    const int t = threadIdx.x;
    {
        int r = t >> 4, c4 = t & 15;
        #pragma unroll
        for (int i = 0; i < 4; ++i) {
            float4 v = *(const float4*)(src + (size_t)(k0 + r + 16 * i) * srl + cb + c4 * 4);
            tile[r + 16 * i][c4 * 4 + 0] = f2bf(v.x);
            tile[r + 16 * i][c4 * 4 + 1] = f2bf(v.y);
            tile[r + 16 * i][c4 * 4 + 2] = f2bf(v.z);
            tile[r + 16 * i][c4 * 4 + 3] = f2bf(v.w);
        }
    }
    __syncthreads();
    {
        int n = t >> 4, k4 = t & 15;
        #pragma unroll
        for (int i = 0; i < 4; ++i) {
            ushort4 v;
            v.x = tile[k4 * 4 + 0][n + 16 * i];
            v.y = tile[k4 * 4 + 1][n + 16 * i];
            v.z = tile[k4 * 4 + 2][n + 16 * i];
            v.w = tile[k4 * 4 + 3][n + 16 * i];
            *(ushort4*)(dst + (size_t)(n0 + n + 16 * i) * dstld + k0 + k4 * 4) = v;
        }
    }
}

// ---------- MFMA bf16 GEMM (VERIFIED r9 staging; r12 z-strides for batching —
// a_z/b_z in ushort elems, c_z in BYTES; pass 0 for 2D)
__global__ __launch_bounds__(256) void gemm_mfma(const ushort* __restrict__ A,
        const ushort* __restrict__ Bt, void* __restrict__ Cv,
        int M, int N, int K, int lda, int ldb, int ldc, int obf16, float scale,
        long a_z, long b_z, long c_z)
{
    __shared__ ushort As[128 * 64];
    __shared__ ushort Bs[128 * 64];
    A  += (size_t)blockIdx.z * a_z;
    Bt += (size_t)blockIdx.z * b_z;
    Cv  = (void*)((char*)Cv + (size_t)blockIdx.z * c_z);
    const int tid = threadIdx.x;
    const int w = tid >> 6, lane = tid & 63;
    const int quad = lane >> 4, l16 = lane & 15;
    const int wm = (w >> 1) * 64, wn = (w & 1) * 64;
    const int m0 = blockIdx.y * 128, n0 = blockIdx.x * 128;

    f32x4 acc[4][4];
    #pragma unroll
    for (int i = 0; i < 4; ++i)
        #pragma unroll
        for (int j = 0; j < 4; ++j) acc[i][j] = (f32x4){0.f, 0.f, 0.f, 0.f};

    const int srow = lane >> 3;
    const int scol = ((lane & 7) * 8) ^ ((srow & 7) << 3);   // (row&7)==srow&7

    for (int k0 = 0; k0 < K; k0 += 64) {
        __syncthreads();
        #pragma unroll
        for (int i = 0; i < 4; ++i) {
            int r = w * 32 + i * 8 + srow;
            gload16(A + (size_t)(m0 + r) * lda + k0 + scol, &As[w * 2048 + i * 512]);
            gload16(Bt + (size_t)(n0 + r) * ldb + k0 + scol, &Bs[w * 2048 + i * 512]);
        }
        __syncthreads();
        #pragma unroll
        for (int kc = 0; kc < 2; ++kc) {
            short8 af[4], bf[4];
            #pragma unroll
            for (int i = 0; i < 4; ++i) {
                int ra = wm + i * 16 + l16;
                int rb = wn + i * 16 + l16;
                af[i] = *(const short8*)&As[ra * 64 + SWZ(ra, kc * 32 + quad * 8)];
                bf[i] = *(const short8*)&Bs[rb * 64 + SWZ(rb, kc * 32 + quad * 8)];
            }
            #pragma unroll
            for (int i = 0; i < 4; ++i)
                #pragma unroll
                for (int j = 0; j < 4; ++j)
                    acc[i][j] = __builtin_amdgcn_mfma_f32_16x16x32_bf16(af[i], bf[j], acc[i][j], 0, 0, 0);
        }
    }
    if (!obf16) {
        float* C = (float*)Cv;
        #pragma unroll
        for (int i = 0; i < 4; ++i)
            #pragma unroll
            for (int r = 0; r < 4; ++r) {
                float* cp = C + (size_t)(m0 + wm + i * 16 + quad * 4 + r) * ldc + n0 + wn + l16;
                #pragma unroll
                for (int j = 0; j < 4; ++j) cp[j * 16] = acc[i][j][r] * scale;
            }
    } else {
        ushort* C = (ushort*)Cv;
        #pragma unroll
        for (int i = 0; i < 4; ++i)
            #pragma unroll
            for (int r = 0; r < 4; ++r) {
                ushort* cp = C + (size_t)(m0 + wm + i * 16 + quad * 4 + r) * ldc + n0 + wn + l16;
                #pragma unroll
                for (int j = 0; j < 4; ++j) cp[j * 16] = f2bf(acc[i][j][r] * scale);
            }
    }
}

// ---------- coalesced rmsnorm, 512 cols, wave per row, bf16 out (VERIFIED r7)
__global__ __launch_bounds__(256) void rms_q_wave(const float* __restrict__ x,
        const float* __restrict__ w, ushort* __restrict__ dst)
{
    const int row = blockIdx.x * 4 + (threadIdx.x >> 6);
    const int lane = threadIdx.x & 63;
    const float* p = x + (size_t)row * 512;
    float4 v0 = *(const float4*)(p + lane * 4);
    float4 v1 = *(const float4*)(p + 256 + lane * 4);
    float ss = v0.x*v0.x + v0.y*v0.y + v0.z*v0.z + v0.w*v0.w
             + v1.x*v1.x + v1.y*v1.y + v1.z*v1.z + v1.w*v1.w;
    #pragma unroll
    for (int m = 1; m < 64; m <<= 1) ss += __shfl_xor(ss, m);
    float inv = rsqrtf(ss * (1.f / 512.f) + 1e-6f);
    float4 w0 = *(const float4*)(w + lane * 4);
    float4 w1 = *(const float4*)(w + 256 + lane * 4);
    ushort* dp = dst + (size_t)row * 512;
    ushort4 o0, o1;
    o0.x = f2bf(v0.x * inv * w0.x); o0.y = f2bf(v0.y * inv * w0.y);
    o0.z = f2bf(v0.z * inv * w0.z); o0.w = f2bf(v0.w * inv * w0.w);
    o1.x = f2bf(v1.x * inv * w1.x); o1.y = f2bf(v1.y * inv * w1.y);
    o1.z = f2bf(v1.z * inv * w1.z); o1.w = f2bf(v1.w * inv * w1.w);
    *(ushort4*)(dp + lane * 4)       = o0;
    *(ushort4*)(dp + 256 + lane * 4) = o1;
}

// ---------- coalesced grouped rmsnorm, 256 cols/group, wave per (row,g) (VERIFIED r7)
__global__ __launch_bounds__(256) void rms_kv_wave(const float* __restrict__ x,
        const float* __restrict__ w, ushort* __restrict__ dst)
{
    const int idx = blockIdx.x * 4 + (threadIdx.x >> 6);   // 0..32767
    const int lane = threadIdx.x & 63;
    const int r = idx >> 2, g = idx & 3;
    const float* p = x + (size_t)r * 1024 + g * 256;
    float4 v = *(const float4*)(p + lane * 4);
    float ss = v.x*v.x + v.y*v.y + v.z*v.z + v.w*v.w;
    #pragma unroll
    for (int m = 1; m < 64; m <<= 1) ss += __shfl_xor(ss, m);
    float inv = rsqrtf(ss * (1.f / 256.f) + 1e-6f);
    float4 wv = *(const float4*)(w + g * 256 + lane * 4);
    ushort4 o;
    o.x = f2bf(v.x * inv * wv.x); o.y = f2bf(v.y * inv * wv.y);
    o.z = f2bf(v.z * inv * wv.z); o.w = f2bf(v.w * inv * wv.w);
    *(ushort4*)(dst + (size_t)r * 1024 + g * 256 + lane * 4) = o;
}

// ---------- V transpose (VERIFIED r5/r6)
__global__ __launch_bounds__(256) void transpose_v(const ushort* __restrict__ KVb,
                                                   ushort* __restrict__ Vt)
{
    __shared__ ushort tile[64][66];
    const int s0 = blockIdx.x * 64;
    const int d0 = blockIdx.y * 64;
    const int bh = blockIdx.z;
    const int b = bh >> 4, h = bh & 15, g = h >> 2, p = h & 3;
    const int t = threadIdx.x;
    const ushort* src = KVb + (size_t)g * 8388608ull + (size_t)(b * 4096) * 1024 + p * 256 + 128;
    {
        int sl = t >> 4, c4 = t & 15;
        #pragma unroll
        for (int i = 0; i < 4; ++i) {
            int s = sl + 16 * i;
            ushort4 v = *(const ushort4*)(src + (size_t)(s0 + s) * 1024 + d0 + c4 * 4);
            tile[s][c4 * 4 + 0] = v.x; tile[s][c4 * 4 + 1] = v.y;
            tile[s][c4 * 4 + 2] = v.z; tile[s][c4 * 4 + 3] = v.w;
        }
    }
    __syncthreads();
    {
        int dl = t >> 4, s4 = t & 15;
        ushort* dst = Vt + (size_t)(b * 16 + h) * 128 * 4096;
        #pragma unroll
        for (int i = 0; i < 4; ++i) {
            int d = dl + 16 * i;
            ushort4 v;
            v.x = tile[s4 * 4 + 0][d]; v.y = tile[s4 * 4 + 1][d];
            v.z = tile[s4 * 4 + 2][d]; v.w = tile[s4 * 4 + 3][d];
            *(ushort4*)(dst + (size_t)(d0 + d) * 4096 + s0 + s4 * 4) = v;
        }
    }
}

// stage one 64x128 K tile + one 128x64 V^T tile at s-offset S0 into (KS,VS)
// 8 gload_lds per thread-group pass -> vmcnt += 8 per wave
#define ATTN_STAGE(KS, VS, S0) do {                                            \
    _Pragma("unroll")                                                          \
    for (int i_ = 0; i_ < 4; ++i_) {                                           \
        int r_ = w * 16 + i_ * 4 + k_r4;                                       \
        gload16(kg + (size_t)((S0) + r_) * 1024 + (k_cb ^ ((r_ & 7) << 3)),    \
                &KS[w * 2048 + i_ * 512]);                                     \
    }                                                                          \
    _Pragma("unroll")                                                          \
    for (int i_ = 0; i_ < 4; ++i_) {                                           \
        int d_ = w * 32 + i_ * 8 + v_r8;                                       \
        gload16(vg + (size_t)d_ * 4096 + (S0) + v_c,                           \
                &VS[w * 2048 + i_ * 512]);                                     \
    }                                                                          \
} while (0)

// full QK^T -> online softmax (defer-max THR=8) -> PV for the tile in (KS,VS)
#define ATTN_COMPUTE(KS, VS) do {                                              \
    f32x4 accS[4];                                                             \
    _Pragma("unroll")                                                          \
    for (int st = 0; st < 4; ++st) accS[st] = (f32x4){0.f, 0.f, 0.f, 0.f};     \
    __builtin_amdgcn_s_setprio(1);                                             \
    _Pragma("unroll")                                                          \
    for (int kc = 0; kc < 4; ++kc) {                                           \
        _Pragma("unroll")                                                      \
        for (int st = 0; st < 4; ++st) {                                       \
            int krow = st * 16 + l16;                                          \
            short8 kf = *(const short8*)&KS[krow * 128 + SWZ(krow, kc * 32 + quad * 8)]; \
            accS[st] = __builtin_amdgcn_mfma_f32_16x16x32_bf16(qf[kc], kf, accS[st], 0, 0, 0); \
        }                                                                      \
    }                                                                          \
    __builtin_amdgcn_s_setprio(0);                                             \
    _Pragma("unroll")                                                          \
    for (int r = 0; r < 4; ++r) {                                              \
        float tm = fmaxf(fmaxf(accS[0][r], accS[1][r]), fmaxf(accS[2][r], accS[3][r])); \
        _Pragma("unroll")                                                      \
        for (int msk = 1; msk < 16; msk <<= 1) tm = fmaxf(tm, __shfl_xor(tm, msk)); \
        if (tm > m_i[r] + 8.f) {                                               \
            float alpha = __expf(m_i[r] - tm);                                 \
            l_i[r] *= alpha;                                                   \
            _Pragma("unroll")                                                  \
            for (int dt = 0; dt < 8; ++dt) accO[dt][r] *= alpha;               \
            m_i[r] = tm;                                                       \
        }                                                                      \
        const float mn = m_i[r];                                               \
        float rs = 0.f;                                                        \
        const int prow = quad * 4 + r;                                         \
        _Pragma("unroll")                                                      \
        for (int st = 0; st < 4; ++st) {                                       \
            float e = __expf(accS[st][r] - mn);                                \
            rs += e;                                                           \
            Ps[(w * 16 + prow) * 64 + SWZ(prow, st * 16 + l16)] = f2bf(e);     \
        }                                                                      \
        _Pragma("unroll")                                                      \
        for (int msk = 1; msk < 16; msk <<= 1) rs += __shfl_xor(rs, msk);      \
        l_i[r] += rs;                                                          \
    }                                                                          \
    short8 pf[2];                                                              \
    _Pragma("unroll")                                                          \
    for (int sc = 0; sc < 2; ++sc)                                             \
        pf[sc] = *(const short8*)&Ps[(w * 16 + l16) * 64 + SWZ(l16, sc * 32 + quad * 8)]; \
    __builtin_amdgcn_s_setprio(1);                                             \
    _Pragma("unroll")                                                          \
    for (int sc = 0; sc < 2; ++sc) {                                           \
        _Pragma("unroll")                                                      \
        for (int dt = 0; dt < 8; ++dt) {                                       \
            int vrow = dt * 16 + l16;                                          \
            short8 vf = *(const short8*)&VS[vrow * 64 + SWZ(vrow, sc * 32 + quad * 8)]; \
            accO[dt] = __builtin_amdgcn_mfma_f32_16x16x32_bf16(pf[sc], vf, accO[dt], 0, 0, 0); \
        }                                                                      \
    }                                                                          \
    __builtin_amdgcn_s_setprio(0);                                             \
} while (0)

#define WAITVM(N) do {                                                         \
    asm volatile("s_waitcnt vmcnt(" #N ")" ::: "memory");                      \
    __builtin_amdgcn_sched_barrier(0);                                         \
} while (0)

// ---------- MFMA flash attention, SPLIT-s=2, round-13: counted-vmcnt pipeline.
// grid (16, 16, 4): z = b*2 + chunk; chunk covers s in [chunk*2048, +2048).
// Double-buffered LDS (73728 B). Per tile: compute(cur) -> s_barrier ->
// STAGE(cur, tile+2) -> vmcnt(8) [tile+1 landed; tile+2's 8 loads stay in
// flight across both barriers and the next compute] -> s_barrier.
__global__ __launch_bounds__(256) void attn_mfma_split(const ushort* __restrict__ Qb,
        const ushort* __restrict__ KVb, const ushort* __restrict__ Vt,
        float* __restrict__ Opart, float* __restrict__ ml)
{
    __shared__ ushort Ks0[64 * 128];     // 16384 B each, swizzled rows
    __shared__ ushort Vs0[128 * 64];
    __shared__ ushort Ks1[64 * 128];
    __shared__ ushort Vs1[128 * 64];
    __shared__ ushort Ps[4 * 16 * 64];   //  8192 B, per-wave 16x64, swizzled

    const int q0 = blockIdx.x * 64;
    const int h = blockIdx.y;
    const int b = blockIdx.z >> 1, chunk = blockIdx.z & 1;
    const int g = h >> 2, p = h & 3;
    const int tid = threadIdx.x;
    const int w = tid >> 6, lane = tid & 63;
    const int quad = lane >> 4, l16 = lane & 15;
    const int sbase = chunk * 2048;

    const ushort* qg = Qb + (size_t)(b * 1024 + q0) * 2048 + h * 128;
    const ushort* kg = KVb + (size_t)g * 8388608ull + (size_t)(b * 4096 + sbase) * 1024 + p * 256;
    const ushort* vg = Vt + (size_t)(b * 16 + h) * 128 * 4096 + sbase;

    // staging geometry (per-lane, hoisted):
    //   K: wave w rows w*16+i*4+(lane>>4); src col = ((lane&15)*8) ^ ((row&7)<<3)
    //   V: wave w rows w*32+i*8+(lane>>3); src col = ((lane&7)*8) ^ ((row&7)<<3)
    const int k_r4 = lane >> 4;
    const int k_cb = (lane & 15) * 8;
    const int v_r8 = lane >> 3;
    const int v_c  = ((lane & 7) * 8) ^ ((v_r8 & 7) << 3);

    // stage Q through Ks0 (manual, swizzled; one-time), pull per-lane fragments
    {
        int kr = tid >> 4, kc8 = (tid & 15) * 8;
        #pragma unroll
        for (int i = 0; i < 4; ++i) {
            int r = kr + 16 * i;
            *(uint4*)&Ks0[r * 128 + SWZ(r, kc8)] = *(const uint4*)(qg + (size_t)r * 2048 + kc8);
        }
    }
    __syncthreads();
    short8 qf[4];
    {
        int qr = w * 16 + l16;
        #pragma unroll
        for (int kc = 0; kc < 4; ++kc)
            qf[kc] = *(const short8*)&Ks0[qr * 128 + SWZ(qr, kc * 32 + quad * 8)];
    }
    __syncthreads();                     // all waves done with Q before DMA lands

    f32x4 accO[8];
    float m_i[4], l_i[4];
    #pragma unroll
    for (int dt = 0; dt < 8; ++dt) accO[dt] = (f32x4){0.f, 0.f, 0.f, 0.f};
    #pragma unroll
    for (int r = 0; r < 4; ++r) { m_i[r] = -INFINITY; l_i[r] = 0.f; }

    // prologue: tiles 0,1 in flight; wait only tile 0 (mine) + barrier (all)
    ATTN_STAGE(Ks0, Vs0, 0);
    ATTN_STAGE(Ks1, Vs1, 64);
    WAITVM(8);
    __builtin_amdgcn_s_barrier();

    // main loop: tiles 0..29 computed; tiles up to 31 staged, 2-deep pipeline
    for (int it2 = 0; it2 < 15; ++it2) {
        const int t0 = it2 * 2;
        ATTN_COMPUTE(Ks0, Vs0);                       // tile t0
        __builtin_amdgcn_s_barrier();                 // all done reading buf0
        ATTN_STAGE(Ks0, Vs0, (t0 + 2) * 64);          // in flight: t0+1(8) + t0+2(8)
        WAITVM(8);                                    // tile t0+1 landed (mine)
        __builtin_amdgcn_s_barrier();                 // tile t0+1 landed (all)
        ATTN_COMPUTE(Ks1, Vs1);                       // tile t0+1
        __builtin_amdgcn_s_barrier();                 // all done reading buf1
        ATTN_STAGE(Ks1, Vs1, (t0 + 3) * 64);          // in flight: t0+2(8) + t0+3(8)
        WAITVM(8);                                    // tile t0+2 landed (mine)
        __builtin_amdgcn_s_barrier();                 // tile t0+2 landed (all)
    }
    // epilogue: tiles 30 (buf0, ready) and 31 (buf1, <=8 in flight)
    ATTN_COMPUTE(Ks0, Vs0);                           // tile 30
    WAITVM(0);                                        // tile 31 landed (mine)
    __builtin_amdgcn_s_barrier();                     // tile 31 landed (all)
    ATTN_COMPUTE(Ks1, Vs1);                           // tile 31

    // epilogue: unnormalized fp32 partials + (m,l)
    const int qrow = q0 + w * 16 + quad * 4;
    float* ob = Opart + (size_t)((chunk * 2 + b) * 1024 + qrow) * 2048 + h * 128 + l16;
    #pragma unroll
    for (int r = 0; r < 4; ++r)
        #pragma unroll
        for (int dt = 0; dt < 8; ++dt)
            ob[(size_t)r * 2048 + dt * 16] = accO[dt][r];
    if (l16 == 0) {
        #pragma unroll
        for (int r = 0; r < 4; ++r) {
            size_t mi = ((size_t)((chunk * 2 + b) * 1024 + qrow + r) * 16 + h) * 2;
            ml[mi] = m_i[r];
            ml[mi + 1] = l_i[r];
        }
    }
}

// ---------- merge the 2 s-chunks: one wave per (b,q,h); lane owns d=lane, lane+64
__global__ __launch_bounds__(256) void attn_merge(const float* __restrict__ Opart,
        const float* __restrict__ ml, ushort* __restrict__ Om)
{
    const int idx = blockIdx.x * 4 + (threadIdx.x >> 6);  // 0..32767
    const int lane = threadIdx.x & 63;
    const int h = idx & 15;
    const int q = (idx >> 4) & 1023;
    const int b = idx >> 14;

    size_t m1i = ((size_t)((0 * 2 + b) * 1024 + q) * 16 + h) * 2;
    size_t m2i = ((size_t)((1 * 2 + b) * 1024 + q) * 16 + h) * 2;
    float m1 = ml[m1i], l1 = ml[m1i + 1];
    float m2 = ml[m2i], l2 = ml[m2i + 1];
    float M = fmaxf(m1, m2);
    float w1 = __expf(m1 - M), w2 = __expf(m2 - M);
    float invL = 1.f / (l1 * w1 + l2 * w2);

    const float* o1 = Opart + (size_t)((0 * 2 + b) * 1024 + q) * 2048 + h * 128;
    const float* o2 = Opart + (size_t)((1 * 2 + b) * 1024 + q) * 2048 + h * 128;
    ushort* ob = Om + (size_t)(b * 1024 + q) * 2048 + h * 128;
    ob[lane]      = f2bf((o1[lane]      * w1 + o2[lane]      * w2) * invL);
    ob[lane + 64] = f2bf((o1[lane + 64] * w1 + o2[lane + 64] * w2) * invL);
}

extern "C" void kernel_launch(void* const* d_in, const int* in_sizes, int n_in,
                              void* d_out, int out_size, void* d_ws, size_t ws_size,
                              hipStream_t stream)
{
    (void)in_sizes; (void)n_in; (void)out_size; (void)ws_size;
    const float* x_q       = (const float*)d_in[0];
    const float* x_kv      = (const float*)d_in[1];
    const float* W_dQ      = (const float*)d_in[2];
    const float* q_norm_w  = (const float*)d_in[3];
    const float* W_uQ      = (const float*)d_in[4];
    const float* W_dKV     = (const float*)d_in[5];
    const float* kv_norm_w = (const float*)d_in[6];
    const float* W_ukv     = (const float*)d_in[7];
    const float* W_o       = (const float*)d_in[8];
    float* out = (float*)d_out;

    float* ws = (float*)d_ws;
    ushort* xkvb       = (ushort*)ws;
    ushort* attn_out_b = (ushort*)ws;
    float*  mlbuf      = ws + 2097152ull;
    ushort* Wot        = (ushort*)(ws + 4194304ull);
    float*  ckv        = ws + 8388608ull;
    float*  Opart      = ws + 8388608ull;                 // aliases dead ckv
    ushort* xqb        = (ushort*)(ws + 8388608ull);      // pre-stage-9 only
    ushort* WdQt       = (ushort*)(ws + 10485760ull);
    float*  q_lat      = ws + 11010048ull;
    ushort* q_lat_b    = (ushort*)(ws + 12058624ull);
    ushort* WuQt       = (ushort*)(ws + 12582912ull);
    ushort* ckv_b      = (ushort*)(ws + 16777216ull);
    ushort* kvgb       = (ushort*)(ws + 20971520ull);
    ushort* vt         = (ushort*)(ws + 37748736ull);
    ushort* qb         = (ushort*)(ws + 46137344ull);
    ushort* WdKVt      = (ushort*)(ws + 48234496ull);
    ushort* Wukvt      = (ushort*)(ws + 49283072ull);

    const float qscale = 0.08838834764831845f;            // 1/sqrt(128)

    // 1-3) q_lat = bf16(x_q) @ bf16(W_dQ)
    cast_bf16<<<2048, 256, 0, stream>>>(x_q, xqb);
    transpose_cast<<<dim3(32, 8, 1), 256, 0, stream>>>(W_dQ, WdQt, 512, 2048, 0, 0, 0);
    gemm_mfma<<<dim3(4, 16), 256, 0, stream>>>(xqb, WdQt, q_lat, 2048, 512, 2048, 2048, 2048, 512, 0, 1.f, 0, 0, 0);
    // 4) rmsnorm -> bf16 (coalesced)
    rms_q_wave<<<512, 256, 0, stream>>>(q_lat, q_norm_w, q_lat_b);
    // 5-6) qb = (q_lat_b @ W_uQ[:, head :128]) * qscale
    transpose_cast<<<dim3(8, 32, 1), 256, 0, stream>>>(W_uQ, WuQt, 3072, 512, 1, 0, 0);
    gemm_mfma<<<dim3(16, 16), 256, 0, stream>>>(q_lat_b, WuQt, qb, 2048, 2048, 512, 512, 512, 2048, 1, qscale, 0, 0, 0);
    // 7-9) ckv = bf16(x_kv) @ bf16(W_dKV[:, :1024])
    cast_bf16<<<8192, 256, 0, stream>>>(x_kv, xkvb);
    transpose_cast<<<dim3(32, 16, 1), 256, 0, stream>>>(W_dKV, WdKVt, 1088, 2048, 0, 0, 0);
    gemm_mfma<<<dim3(8, 64), 256, 0, stream>>>(xkvb, WdKVt, ckv, 8192, 1024, 2048, 2048, 2048, 1024, 0, 1.f, 0, 0, 0);
    // 10) grouped rmsnorm -> bf16 (coalesced)
    rms_kv_wave<<<8192, 256, 0, stream>>>(ckv, kv_norm_w, ckv_b);
    // 11-12) kv up-projection, all 4 groups in ONE launch (z = group)
    transpose_cast<<<dim3(4, 16, 4), 256, 0, stream>>>(W_ukv, Wukvt, 1024, 256, 0, 262144, 262144);
    gemm_mfma<<<dim3(8, 64, 4), 256, 0, stream>>>(ckv_b, Wukvt, kvgb,
                                                  8192, 1024, 256, 1024, 256, 1024, 1, 1.f,
                                                  256, 262144, 16777216);
    // 13) V transpose
    transpose_v<<<dim3(64, 2, 32), 256, 0, stream>>>(kvgb, vt);
    // 14) split-s MFMA flash attention + merge
    attn_mfma_split<<<dim3(16, 16, 4), 256, 0, stream>>>(qb, kvgb, vt, Opart, mlbuf);
    attn_merge<<<8192, 256, 0, stream>>>(Opart, mlbuf, attn_out_b);
    // 15-16) out = attn_out_b @ bf16(W_o)
    transpose_cast<<<dim3(32, 32, 1), 256, 0, stream>>>(W_o, Wot, 2048, 2048, 0, 0, 0);
    gemm_mfma<<<dim3(16, 16), 256, 0, stream>>>(attn_out_b, Wot, out, 2048, 2048, 2048, 2048, 2048, 2048, 0, 1.f, 0, 0, 0);
}

// Round 7
// 506.385 us; speedup vs baseline: 1.6273x; 1.0997x over previous
//
#include <hip/hip_runtime.h>
#include <hip/hip_bf16.h>
#include <math.h>

// GLA cross-attention — round 14:
//  r13 post-mortem: counted-vmcnt pipeline executed cleanly (WRITE 33MB, raw
//  barriers) and was EXACTLY neutral (198us) -> staging latency is NOT the
//  bottleneck; 5 staging structures all land 198-220us. The stall is the
//  per-iteration softmax: 8 dependent __shfl_xor ops (ds_swizzle, ~30cyc each)
//  x 4 rows between QK^T and PV, with ~2 blocks/CU of TLP.
//  r14 (semantics-identical, chains removed from common path):
//   (a) ballot-gated lazy group-max: trigger (group_max > m_i+8) computed as
//       any(lane_max > m_i+8) via __ballot + quad slice test. Shfl max-reduce
//       runs ONLY when triggered (first tile + rare growth).
//   (b) lane-partial l_i (alpha is group-uniform so rescale stays correct);
//       single shfl sum-reduce per row in the EPILOGUE (amortized 32x).
//  Everything else byte-identical to PASSING r13.
//
// ws float-offset map (alias notes; top = 49,807,360 f = 199.2 MB):
//   attn_out_b u16 @ 0 | ml f32 @ 2,097,152 | Wot u16 @ f4,194,304
//   xkvb u16 @ 0 (dead after stage 9) | ckv f32 @ 8,388,608 (dead after 10)
//   Opart f32 @ 8,388,608 (aliases dead ckv)
//   xqb/WdQt/q_lat/q_lat_b/WuQt in 8,388,608..13,631,488 (dead pre-stage-9)
//   ckv_b u16 @ 16,777,216 | kvgb u16 @ 20,971,520 | vt u16 @ 37,748,736
//   qb u16 @ 46,137,344 | WdKVt u16 @ 48,234,496 | Wukvt u16 @ 49,283,072

typedef __attribute__((ext_vector_type(8))) short short8;
typedef __attribute__((ext_vector_type(4))) float f32x4;

__device__ __forceinline__ ushort f2bf(float x) {
    __hip_bfloat16 h = __float2bfloat16(x);
    return *reinterpret_cast<ushort*>(&h);
}

// XOR swizzle in units of shorts: permutes 8-short (16B) blocks within each
// 64/128-short row by the low 3 row bits. Bijective; keeps 16B alignment.
#define SWZ(row, col) ((col) ^ (((row) & 7) << 3))

// async global->LDS, 16B per lane. LDS dest wave-uniform; global src per-lane.
__device__ __forceinline__ void gload16(const ushort* g, ushort* l)
{
    __builtin_amdgcn_global_load_lds(
        (const __attribute__((address_space(1))) void*)g,
        (__attribute__((address_space(3))) void*)l, 16, 0, 0);
}

// ---------- elementwise fp32 -> bf16 cast, 8 elems/thread (VERIFIED r6)
__global__ __launch_bounds__(256) void cast_bf16(const float* __restrict__ src,
        ushort* __restrict__ dst)
{
    size_t i = ((size_t)blockIdx.x * 256 + threadIdx.x) * 8;
    float4 a = *(const float4*)(src + i);
    float4 b = *(const float4*)(src + i + 4);
    ushort u[8] = {f2bf(a.x), f2bf(a.y), f2bf(a.z), f2bf(a.w),
                   f2bf(b.x), f2bf(b.y), f2bf(b.z), f2bf(b.w)};
    *(uint4*)(dst + i) = *(uint4*)u;
}

// ---------- transpose + cast (VERIFIED r6)
__global__ __launch_bounds__(256) void transpose_cast(const float* __restrict__ src,
        ushort* __restrict__ dst, int srl, int dstld, int remap,
        long src_z, long dst_z)
{
    __shared__ ushort tile[64][68];
    const int k0 = blockIdx.x * 64;
    const int n0 = blockIdx.y * 64;
    src += (size_t)blockIdx.z * src_z;
    dst += (size_t)blockIdx.z * dst_z;
    const int cb = n0 + (remap ? (n0 >> 7) * 64 : 0);
    const int t = threadIdx.x;
    {
        int r = t >> 4, c4 = t & 15;
        #pragma unroll
        for (int i = 0; i < 4; ++i) {
            float4 v = *(const float4*)(src + (size_t)(k0 + r + 16 * i) * srl + cb + c4 * 4);
            tile[r + 16 * i][c4 * 4 + 0] = f2bf(v.x);
            tile[r + 16 * i][c4 * 4 + 1] = f2bf(v.y);
            tile[r + 16 * i][c4 * 4 + 2] = f2bf(v.z);
            tile[r + 16 * i][c4 * 4 + 3] = f2bf(v.w);
        }
    }
    __syncthreads();
    {
        int n = t >> 4, k4 = t & 15;
        #pragma unroll
        for (int i = 0; i < 4; ++i) {
            ushort4 v;
            v.x = tile[k4 * 4 + 0][n + 16 * i];
            v.y = tile[k4 * 4 + 1][n + 16 * i];
            v.z = tile[k4 * 4 + 2][n + 16 * i];
            v.w = tile[k4 * 4 + 3][n + 16 * i];
            *(ushort4*)(dst + (size_t)(n0 + n + 16 * i) * dstld + k0 + k4 * 4) = v;
        }
    }
}

// ---------- MFMA bf16 GEMM (VERIFIED r9 staging; r12 z-strides for batching —
// a_z/b_z in ushort elems, c_z in BYTES; pass 0 for 2D)
__global__ __launch_bounds__(256) void gemm_mfma(const ushort* __restrict__ A,
        const ushort* __restrict__ Bt, void* __restrict__ Cv,
        int M, int N, int K, int lda, int ldb, int ldc, int obf16, float scale,
        long a_z, long b_z, long c_z)
{
    __shared__ ushort As[128 * 64];
    __shared__ ushort Bs[128 * 64];
    A  += (size_t)blockIdx.z * a_z;
    Bt += (size_t)blockIdx.z * b_z;
    Cv  = (void*)((char*)Cv + (size_t)blockIdx.z * c_z);
    const int tid = threadIdx.x;
    const int w = tid >> 6, lane = tid & 63;
    const int quad = lane >> 4, l16 = lane & 15;
    const int wm = (w >> 1) * 64, wn = (w & 1) * 64;
    const int m0 = blockIdx.y * 128, n0 = blockIdx.x * 128;

    f32x4 acc[4][4];
    #pragma unroll
    for (int i = 0; i < 4; ++i)
        #pragma unroll
        for (int j = 0; j < 4; ++j) acc[i][j] = (f32x4){0.f, 0.f, 0.f, 0.f};

    const int srow = lane >> 3;
    const int scol = ((lane & 7) * 8) ^ ((srow & 7) << 3);   // (row&7)==srow&7

    for (int k0 = 0; k0 < K; k0 += 64) {
        __syncthreads();
        #pragma unroll
        for (int i = 0; i < 4; ++i) {
            int r = w * 32 + i * 8 + srow;
            gload16(A + (size_t)(m0 + r) * lda + k0 + scol, &As[w * 2048 + i * 512]);
            gload16(Bt + (size_t)(n0 + r) * ldb + k0 + scol, &Bs[w * 2048 + i * 512]);
        }
        __syncthreads();
        #pragma unroll
        for (int kc = 0; kc < 2; ++kc) {
            short8 af[4], bf[4];
            #pragma unroll
            for (int i = 0; i < 4; ++i) {
                int ra = wm + i * 16 + l16;
                int rb = wn + i * 16 + l16;
                af[i] = *(const short8*)&As[ra * 64 + SWZ(ra, kc * 32 + quad * 8)];
                bf[i] = *(const short8*)&Bs[rb * 64 + SWZ(rb, kc * 32 + quad * 8)];
            }
            #pragma unroll
            for (int i = 0; i < 4; ++i)
                #pragma unroll
                for (int j = 0; j < 4; ++j)
                    acc[i][j] = __builtin_amdgcn_mfma_f32_16x16x32_bf16(af[i], bf[j], acc[i][j], 0, 0, 0);
        }
    }
    if (!obf16) {
        float* C = (float*)Cv;
        #pragma unroll
        for (int i = 0; i < 4; ++i)
            #pragma unroll
            for (int r = 0; r < 4; ++r) {
                float* cp = C + (size_t)(m0 + wm + i * 16 + quad * 4 + r) * ldc + n0 + wn + l16;
                #pragma unroll
                for (int j = 0; j < 4; ++j) cp[j * 16] = acc[i][j][r] * scale;
            }
    } else {
        ushort* C = (ushort*)Cv;
        #pragma unroll
        for (int i = 0; i < 4; ++i)
            #pragma unroll
            for (int r = 0; r < 4; ++r) {
                ushort* cp = C + (size_t)(m0 + wm + i * 16 + quad * 4 + r) * ldc + n0 + wn + l16;
                #pragma unroll
                for (int j = 0; j < 4; ++j) cp[j * 16] = f2bf(acc[i][j][r] * scale);
            }
    }
}

// ---------- coalesced rmsnorm, 512 cols, wave per row, bf16 out (VERIFIED r7)
__global__ __launch_bounds__(256) void rms_q_wave(const float* __restrict__ x,
        const float* __restrict__ w, ushort* __restrict__ dst)
{
    const int row = blockIdx.x * 4 + (threadIdx.x >> 6);
    const int lane = threadIdx.x & 63;
    const float* p = x + (size_t)row * 512;
    float4 v0 = *(const float4*)(p + lane * 4);
    float4 v1 = *(const float4*)(p + 256 + lane * 4);
    float ss = v0.x*v0.x + v0.y*v0.y + v0.z*v0.z + v0.w*v0.w
             + v1.x*v1.x + v1.y*v1.y + v1.z*v1.z + v1.w*v1.w;
    #pragma unroll
    for (int m = 1; m < 64; m <<= 1) ss += __shfl_xor(ss, m);
    float inv = rsqrtf(ss * (1.f / 512.f) + 1e-6f);
    float4 w0 = *(const float4*)(w + lane * 4);
    float4 w1 = *(const float4*)(w + 256 + lane * 4);
    ushort* dp = dst + (size_t)row * 512;
    ushort4 o0, o1;
    o0.x = f2bf(v0.x * inv * w0.x); o0.y = f2bf(v0.y * inv * w0.y);
    o0.z = f2bf(v0.z * inv * w0.z); o0.w = f2bf(v0.w * inv * w0.w);
    o1.x = f2bf(v1.x * inv * w1.x); o1.y = f2bf(v1.y * inv * w1.y);
    o1.z = f2bf(v1.z * inv * w1.z); o1.w = f2bf(v1.w * inv * w1.w);
    *(ushort4*)(dp + lane * 4)       = o0;
    *(ushort4*)(dp + 256 + lane * 4) = o1;
}

// ---------- coalesced grouped rmsnorm, 256 cols/group, wave per (row,g) (VERIFIED r7)
__global__ __launch_bounds__(256) void rms_kv_wave(const float* __restrict__ x,
        const float* __restrict__ w, ushort* __restrict__ dst)
{
    const int idx = blockIdx.x * 4 + (threadIdx.x >> 6);   // 0..32767
    const int lane = threadIdx.x & 63;
    const int r = idx >> 2, g = idx & 3;
    const float* p = x + (size_t)r * 1024 + g * 256;
    float4 v = *(const float4*)(p + lane * 4);
    float ss = v.x*v.x + v.y*v.y + v.z*v.z + v.w*v.w;
    #pragma unroll
    for (int m = 1; m < 64; m <<= 1) ss += __shfl_xor(ss, m);
    float inv = rsqrtf(ss * (1.f / 256.f) + 1e-6f);
    float4 wv = *(const float4*)(w + g * 256 + lane * 4);
    ushort4 o;
    o.x = f2bf(v.x * inv * wv.x); o.y = f2bf(v.y * inv * wv.y);
    o.z = f2bf(v.z * inv * wv.z); o.w = f2bf(v.w * inv * wv.w);
    *(ushort4*)(dst + (size_t)r * 1024 + g * 256 + lane * 4) = o;
}

// ---------- V transpose (VERIFIED r5/r6)
__global__ __launch_bounds__(256) void transpose_v(const ushort* __restrict__ KVb,
                                                   ushort* __restrict__ Vt)
{
    __shared__ ushort tile[64][66];
    const int s0 = blockIdx.x * 64;
    const int d0 = blockIdx.y * 64;
    const int bh = blockIdx.z;
    const int b = bh >> 4, h = bh & 15, g = h >> 2, p = h & 3;
    const int t = threadIdx.x;
    const ushort* src = KVb + (size_t)g * 8388608ull + (size_t)(b * 4096) * 1024 + p * 256 + 128;
    {
        int sl = t >> 4, c4 = t & 15;
        #pragma unroll
        for (int i = 0; i < 4; ++i) {
            int s = sl + 16 * i;
            ushort4 v = *(const ushort4*)(src + (size_t)(s0 + s) * 1024 + d0 + c4 * 4);
            tile[s][c4 * 4 + 0] = v.x; tile[s][c4 * 4 + 1] = v.y;
            tile[s][c4 * 4 + 2] = v.z; tile[s][c4 * 4 + 3] = v.w;
        }
    }
    __syncthreads();
    {
        int dl = t >> 4, s4 = t & 15;
        ushort* dst = Vt + (size_t)(b * 16 + h) * 128 * 4096;
        #pragma unroll
        for (int i = 0; i < 4; ++i) {
            int d = dl + 16 * i;
            ushort4 v;
            v.x = tile[s4 * 4 + 0][d]; v.y = tile[s4 * 4 + 1][d];
            v.z = tile[s4 * 4 + 2][d]; v.w = tile[s4 * 4 + 3][d];
            *(ushort4*)(dst + (size_t)(d0 + d) * 4096 + s0 + s4 * 4) = v;
        }
    }
}

// stage one 64x128 K tile + one 128x64 V^T tile at s-offset S0 into (KS,VS)
// 8 gload_lds per thread -> vmcnt += 8 per wave
#define ATTN_STAGE(KS, VS, S0) do {                                            \
    _Pragma("unroll")                                                          \
    for (int i_ = 0; i_ < 4; ++i_) {                                           \
        int r_ = w * 16 + i_ * 4 + k_r4;                                       \
        gload16(kg + (size_t)((S0) + r_) * 1024 + (k_cb ^ ((r_ & 7) << 3)),    \
                &KS[w * 2048 + i_ * 512]);                                     \
    }                                                                          \
    _Pragma("unroll")                                                          \
    for (int i_ = 0; i_ < 4; ++i_) {                                           \
        int d_ = w * 32 + i_ * 8 + v_r8;                                       \
        gload16(vg + (size_t)d_ * 4096 + (S0) + v_c,                           \
                &VS[w * 2048 + i_ * 512]);                                     \
    }                                                                          \
} while (0)

// QK^T -> online softmax (ballot-gated lazy max, lane-partial l) -> PV.
// Common path has ZERO cross-lane ops: per-lane max + __ballot trigger test;
// the shfl max-reduce runs only when the group's max grew past m_i+8.
// l_i[r] is a LANE-PARTIAL sum (alpha uniform in group -> rescale correct);
// reduced once in the epilogue.
#define ATTN_COMPUTE(KS, VS) do {                                              \
    f32x4 accS[4];                                                             \
    _Pragma("unroll")                                                          \
    for (int st = 0; st < 4; ++st) accS[st] = (f32x4){0.f, 0.f, 0.f, 0.f};     \
    __builtin_amdgcn_s_setprio(1);                                             \
    _Pragma("unroll")                                                          \
    for (int kc = 0; kc < 4; ++kc) {                                           \
        _Pragma("unroll")                                                      \
        for (int st = 0; st < 4; ++st) {                                       \
            int krow = st * 16 + l16;                                          \
            short8 kf = *(const short8*)&KS[krow * 128 + SWZ(krow, kc * 32 + quad * 8)]; \
            accS[st] = __builtin_amdgcn_mfma_f32_16x16x32_bf16(qf[kc], kf, accS[st], 0, 0, 0); \
        }                                                                      \
    }                                                                          \
    __builtin_amdgcn_s_setprio(0);                                             \
    _Pragma("unroll")                                                          \
    for (int r = 0; r < 4; ++r) {                                              \
        float tm = fmaxf(fmaxf(accS[0][r], accS[1][r]), fmaxf(accS[2][r], accS[3][r])); \
        unsigned long long bal = __ballot(tm > m_i[r] + 8.f);                  \
        if ((bal >> (quad * 16)) & 0xFFFFull) {   /* group-uniform, rare */    \
            _Pragma("unroll")                                                  \
            for (int msk = 1; msk < 16; msk <<= 1) tm = fmaxf(tm, __shfl_xor(tm, msk)); \
            float alpha = __expf(m_i[r] - tm);                                 \
            l_i[r] *= alpha;                                                   \
            _Pragma("unroll")                                                  \
            for (int dt = 0; dt < 8; ++dt) accO[dt][r] *= alpha;               \
            m_i[r] = tm;                                                       \
        }                                                                      \
        const float mn = m_i[r];                                               \
        const int prow = quad * 4 + r;                                         \
        _Pragma("unroll")                                                      \
        for (int st = 0; st < 4; ++st) {                                       \
            float e = __expf(accS[st][r] - mn);                                \
            l_i[r] += e;                           /* lane-partial */          \
            Ps[(w * 16 + prow) * 64 + SWZ(prow, st * 16 + l16)] = f2bf(e);     \
        }                                                                      \
    }                                                                          \
    short8 pf[2];                                                              \
    _Pragma("unroll")                                                          \
    for (int sc = 0; sc < 2; ++sc)                                             \
        pf[sc] = *(const short8*)&Ps[(w * 16 + l16) * 64 + SWZ(l16, sc * 32 + quad * 8)]; \
    __builtin_amdgcn_s_setprio(1);                                             \
    _Pragma("unroll")                                                          \
    for (int sc = 0; sc < 2; ++sc) {                                           \
        _Pragma("unroll")                                                      \
        for (int dt = 0; dt < 8; ++dt) {                                       \
            int vrow = dt * 16 + l16;                                          \
            short8 vf = *(const short8*)&VS[vrow * 64 + SWZ(vrow, sc * 32 + quad * 8)]; \
            accO[dt] = __builtin_amdgcn_mfma_f32_16x16x32_bf16(pf[sc], vf, accO[dt], 0, 0, 0); \
        }                                                                      \
    }                                                                          \
    __builtin_amdgcn_s_setprio(0);                                             \
} while (0)

#define WAITVM(N) do {                                                         \
    asm volatile("s_waitcnt vmcnt(" #N ")" ::: "memory");                      \
    __builtin_amdgcn_sched_barrier(0);                                         \
} while (0)

// ---------- MFMA flash attention, SPLIT-s=2, round-14.
// grid (16, 16, 4): z = b*2 + chunk; chunk covers s in [chunk*2048, +2048).
// r13 counted-vmcnt pipeline (verified): compute(cur) -> s_barrier ->
// STAGE(cur, tile+2) -> vmcnt(8) -> s_barrier. r14 softmax de-chained.
__global__ __launch_bounds__(256) void attn_mfma_split(const ushort* __restrict__ Qb,
        const ushort* __restrict__ KVb, const ushort* __restrict__ Vt,
        float* __restrict__ Opart, float* __restrict__ ml)
{
    __shared__ ushort Ks0[64 * 128];     // 16384 B each, swizzled rows
    __shared__ ushort Vs0[128 * 64];
    __shared__ ushort Ks1[64 * 128];
    __shared__ ushort Vs1[128 * 64];
    __shared__ ushort Ps[4 * 16 * 64];   //  8192 B, per-wave 16x64, swizzled

    const int q0 = blockIdx.x * 64;
    const int h = blockIdx.y;
    const int b = blockIdx.z >> 1, chunk = blockIdx.z & 1;
    const int g = h >> 2, p = h & 3;
    const int tid = threadIdx.x;
    const int w = tid >> 6, lane = tid & 63;
    const int quad = lane >> 4, l16 = lane & 15;
    const int sbase = chunk * 2048;

    const ushort* qg = Qb + (size_t)(b * 1024 + q0) * 2048 + h * 128;
    const ushort* kg = KVb + (size_t)g * 8388608ull + (size_t)(b * 4096 + sbase) * 1024 + p * 256;
    const ushort* vg = Vt + (size_t)(b * 16 + h) * 128 * 4096 + sbase;

    // staging geometry (per-lane, hoisted):
    const int k_r4 = lane >> 4;
    const int k_cb = (lane & 15) * 8;
    const int v_r8 = lane >> 3;
    const int v_c  = ((lane & 7) * 8) ^ ((v_r8 & 7) << 3);

    // stage Q through Ks0 (manual, swizzled; one-time), pull per-lane fragments
    {
        int kr = tid >> 4, kc8 = (tid & 15) * 8;
        #pragma unroll
        for (int i = 0; i < 4; ++i) {
            int r = kr + 16 * i;
            *(uint4*)&Ks0[r * 128 + SWZ(r, kc8)] = *(const uint4*)(qg + (size_t)r * 2048 + kc8);
        }
    }
    __syncthreads();
    short8 qf[4];
    {
        int qr = w * 16 + l16;
        #pragma unroll
        for (int kc = 0; kc < 4; ++kc)
            qf[kc] = *(const short8*)&Ks0[qr * 128 + SWZ(qr, kc * 32 + quad * 8)];
    }
    __syncthreads();                     // all waves done with Q before DMA lands

    f32x4 accO[8];
    float m_i[4], l_i[4];
    #pragma unroll
    for (int dt = 0; dt < 8; ++dt) accO[dt] = (f32x4){0.f, 0.f, 0.f, 0.f};
    #pragma unroll
    for (int r = 0; r < 4; ++r) { m_i[r] = -INFINITY; l_i[r] = 0.f; }

    // prologue: tiles 0,1 in flight; wait only tile 0 (mine) + barrier (all)
    ATTN_STAGE(Ks0, Vs0, 0);
    ATTN_STAGE(Ks1, Vs1, 64);
    WAITVM(8);
    __builtin_amdgcn_s_barrier();

    // main loop: 2-deep counted-vmcnt pipeline (verified r13)
    for (int it2 = 0; it2 < 15; ++it2) {
        const int t0 = it2 * 2;
        ATTN_COMPUTE(Ks0, Vs0);                       // tile t0
        __builtin_amdgcn_s_barrier();                 // all done reading buf0
        ATTN_STAGE(Ks0, Vs0, (t0 + 2) * 64);          // in flight: t0+1(8) + t0+2(8)
        WAITVM(8);                                    // tile t0+1 landed (mine)
        __builtin_amdgcn_s_barrier();                 // tile t0+1 landed (all)
        ATTN_COMPUTE(Ks1, Vs1);                       // tile t0+1
        __builtin_amdgcn_s_barrier();                 // all done reading buf1
        ATTN_STAGE(Ks1, Vs1, (t0 + 3) * 64);          // in flight: t0+2(8) + t0+3(8)
        WAITVM(8);                                    // tile t0+2 landed (mine)
        __builtin_amdgcn_s_barrier();                 // tile t0+2 landed (all)
    }
    // epilogue tiles: 30 (buf0, ready) and 31 (buf1, <=8 in flight)
    ATTN_COMPUTE(Ks0, Vs0);                           // tile 30
    WAITVM(0);                                        // tile 31 landed (mine)
    __builtin_amdgcn_s_barrier();                     // tile 31 landed (all)
    ATTN_COMPUTE(Ks1, Vs1);                           // tile 31

    // reduce lane-partial l across the 16-lane row group (once per kernel)
    #pragma unroll
    for (int r = 0; r < 4; ++r)
        #pragma unroll
        for (int msk = 1; msk < 16; msk <<= 1)
            l_i[r] += __shfl_xor(l_i[r], msk);

    // epilogue: unnormalized fp32 partials + (m,l)
    const int qrow = q0 + w * 16 + quad * 4;
    float* ob = Opart + (size_t)((chunk * 2 + b) * 1024 + qrow) * 2048 + h * 128 + l16;
    #pragma unroll
    for (int r = 0; r < 4; ++r)
        #pragma unroll
        for (int dt = 0; dt < 8; ++dt)
            ob[(size_t)r * 2048 + dt * 16] = accO[dt][r];
    if (l16 == 0) {
        #pragma unroll
        for (int r = 0; r < 4; ++r) {
            size_t mi = ((size_t)((chunk * 2 + b) * 1024 + qrow + r) * 16 + h) * 2;
            ml[mi] = m_i[r];
            ml[mi + 1] = l_i[r];
        }
    }
}

// ---------- merge the 2 s-chunks: one wave per (b,q,h); lane owns d=lane, lane+64
__global__ __launch_bounds__(256) void attn_merge(const float* __restrict__ Opart,
        const float* __restrict__ ml, ushort* __restrict__ Om)
{
    const int idx = blockIdx.x * 4 + (threadIdx.x >> 6);  // 0..32767
    const int lane = threadIdx.x & 63;
    const int h = idx & 15;
    const int q = (idx >> 4) & 1023;
    const int b = idx >> 14;

    size_t m1i = ((size_t)((0 * 2 + b) * 1024 + q) * 16 + h) * 2;
    size_t m2i = ((size_t)((1 * 2 + b) * 1024 + q) * 16 + h) * 2;
    float m1 = ml[m1i], l1 = ml[m1i + 1];
    float m2 = ml[m2i], l2 = ml[m2i + 1];
    float M = fmaxf(m1, m2);
    float w1 = __expf(m1 - M), w2 = __expf(m2 - M);
    float invL = 1.f / (l1 * w1 + l2 * w2);

    const float* o1 = Opart + (size_t)((0 * 2 + b) * 1024 + q) * 2048 + h * 128;
    const float* o2 = Opart + (size_t)((1 * 2 + b) * 1024 + q) * 2048 + h * 128;
    ushort* ob = Om + (size_t)(b * 1024 + q) * 2048 + h * 128;
    ob[lane]      = f2bf((o1[lane]      * w1 + o2[lane]      * w2) * invL);
    ob[lane + 64] = f2bf((o1[lane + 64] * w1 + o2[lane + 64] * w2) * invL);
}

extern "C" void kernel_launch(void* const* d_in, const int* in_sizes, int n_in,
                              void* d_out, int out_size, void* d_ws, size_t ws_size,
                              hipStream_t stream)
{
    (void)in_sizes; (void)n_in; (void)out_size; (void)ws_size;
    const float* x_q       = (const float*)d_in[0];
    const float* x_kv      = (const float*)d_in[1];
    const float* W_dQ      = (const float*)d_in[2];
    const float* q_norm_w  = (const float*)d_in[3];
    const float* W_uQ      = (const float*)d_in[4];
    const float* W_dKV     = (const float*)d_in[5];
    const float* kv_norm_w = (const float*)d_in[6];
    const float* W_ukv     = (const float*)d_in[7];
    const float* W_o       = (const float*)d_in[8];
    float* out = (float*)d_out;

    float* ws = (float*)d_ws;
    ushort* xkvb       = (ushort*)ws;
    ushort* attn_out_b = (ushort*)ws;
    float*  mlbuf      = ws + 2097152ull;
    ushort* Wot        = (ushort*)(ws + 4194304ull);
    float*  ckv        = ws + 8388608ull;
    float*  Opart      = ws + 8388608ull;                 // aliases dead ckv
    ushort* xqb        = (ushort*)(ws + 8388608ull);      // pre-stage-9 only
    ushort* WdQt       = (ushort*)(ws + 10485760ull);
    float*  q_lat      = ws + 11010048ull;
    ushort* q_lat_b    = (ushort*)(ws + 12058624ull);
    ushort* WuQt       = (ushort*)(ws + 12582912ull);
    ushort* ckv_b      = (ushort*)(ws + 16777216ull);
    ushort* kvgb       = (ushort*)(ws + 20971520ull);
    ushort* vt         = (ushort*)(ws + 37748736ull);
    ushort* qb         = (ushort*)(ws + 46137344ull);
    ushort* WdKVt      = (ushort*)(ws + 48234496ull);
    ushort* Wukvt      = (ushort*)(ws + 49283072ull);

    const float qscale = 0.08838834764831845f;            // 1/sqrt(128)

    // 1-3) q_lat = bf16(x_q) @ bf16(W_dQ)
    cast_bf16<<<2048, 256, 0, stream>>>(x_q, xqb);
    transpose_cast<<<dim3(32, 8, 1), 256, 0, stream>>>(W_dQ, WdQt, 512, 2048, 0, 0, 0);
    gemm_mfma<<<dim3(4, 16), 256, 0, stream>>>(xqb, WdQt, q_lat, 2048, 512, 2048, 2048, 2048, 512, 0, 1.f, 0, 0, 0);
    // 4) rmsnorm -> bf16 (coalesced)
    rms_q_wave<<<512, 256, 0, stream>>>(q_lat, q_norm_w, q_lat_b);
    // 5-6) qb = (q_lat_b @ W_uQ[:, head :128]) * qscale
    transpose_cast<<<dim3(8, 32, 1), 256, 0, stream>>>(W_uQ, WuQt, 3072, 512, 1, 0, 0);
    gemm_mfma<<<dim3(16, 16), 256, 0, stream>>>(q_lat_b, WuQt, qb, 2048, 2048, 512, 512, 512, 2048, 1, qscale, 0, 0, 0);
    // 7-9) ckv = bf16(x_kv) @ bf16(W_dKV[:, :1024])
    cast_bf16<<<8192, 256, 0, stream>>>(x_kv, xkvb);
    transpose_cast<<<dim3(32, 16, 1), 256, 0, stream>>>(W_dKV, WdKVt, 1088, 2048, 0, 0, 0);
    gemm_mfma<<<dim3(8, 64), 256, 0, stream>>>(xkvb, WdKVt, ckv, 8192, 1024, 2048, 2048, 2048, 1024, 0, 1.f, 0, 0, 0);
    // 10) grouped rmsnorm -> bf16 (coalesced)
    rms_kv_wave<<<8192, 256, 0, stream>>>(ckv, kv_norm_w, ckv_b);
    // 11-12) kv up-projection, all 4 groups in ONE launch (z = group)
    transpose_cast<<<dim3(4, 16, 4), 256, 0, stream>>>(W_ukv, Wukvt, 1024, 256, 0, 262144, 262144);
    gemm_mfma<<<dim3(8, 64, 4), 256, 0, stream>>>(ckv_b, Wukvt, kvgb,
                                                  8192, 1024, 256, 1024, 256, 1024, 1, 1.f,
                                                  256, 262144, 16777216);
    // 13) V transpose
    transpose_v<<<dim3(64, 2, 32), 256, 0, stream>>>(kvgb, vt);
    // 14) split-s MFMA flash attention + merge
    attn_mfma_split<<<dim3(16, 16, 4), 256, 0, stream>>>(qb, kvgb, vt, Opart, mlbuf);
    attn_merge<<<8192, 256, 0, stream>>>(Opart, mlbuf, attn_out_b);
    // 15-16) out = attn_out_b @ bf16(W_o)
    transpose_cast<<<dim3(32, 32, 1), 256, 0, stream>>>(W_o, Wot, 2048, 2048, 0, 0, 0);
    gemm_mfma<<<dim3(16, 16), 256, 0, stream>>>(attn_out_b, Wot, out, 2048, 2048, 2048, 2048, 2048, 2048, 0, 1.f, 0, 0, 0);
}